// Round 7
// baseline (322.576 us; speedup 1.0000x reference)
//
#include <hip/hip_runtime.h>
#include <math.h>

// Problem constants (from setup_inputs)
#define T_TOTAL 2097152
#define A_DIM   18
#define GAMMA_D 0.99

#define CHUNK 256
#define NC    (T_TOTAL / CHUNK)        // 8192 chunks
#define KTR   14                       // G^14 ~ 2e-16, G = 0.99^256 ~ 0.076
#define CPB   4                        // chunks per block
#define NB    (NC / CPB)               // 2048 blocks
#define BLK   256                      // 4 waves; 2 row-pairs (4 rows)/thread

// ---------------------------------------------------------------------------
// Single fused kernel, R5-proven geometry + atomic finalize.
//  phase 0a: issue ALL ep_rs loads (window 5x float4 + own chunk) FIRST —
//            phase 1's wait on r then leaves weight loads in flight (in-order
//            vmcnt queue: waiting on the OLDEST loads keeps newer ones live)
//  phase 0b: issue pair-0 weight/act loads (consumed in phase 3)
//  phase 1:  window sums L[c0+1..c0+17] via wave reduce -> LDS
//  phase 2:  wave wv computes own-chunk d (bit-exact lane suffix scan) -> LDS
//  phase 3:  two row-pairs of register logsumexp (exact reference op order);
//            pair-1 loads issued before pair-0 compute
//  epilogue: block reduce -> 3 f64 device atomicAdds; last block finalizes.
__global__ __launch_bounds__(BLK, 4)
void k_mega(const float* __restrict__ wgt, const int* __restrict__ act,
            const float* __restrict__ r, double* __restrict__ acc,
            unsigned int* __restrict__ flag, float* __restrict__ out) {
    __shared__ double ldsL[17];               // window chunk-sums
    __shared__ double ldsD[CPB * CHUNK];      // d for the block's 1024 rows (8 KB)
    __shared__ double red[12];
    const int tid  = threadIdx.x;
    const int lane = tid & 63, wv = tid >> 6;      // wv in 0..3
    const int c0   = blockIdx.x * CPB;
    const double g  = GAMMA_D;
    const double G_ = pow(g, 256.0);
    const double w4 = pow(g, (double)(4 * lane));

    // ---- phase 0a: ep_rs loads first (window k = wv+4i, i=0..4; own chunk) --
    float4 rwin[5];
    #pragma unroll
    for (int i = 0; i < 5; ++i) {
        const int k  = wv + 4 * i;
        const int cc = c0 + 1 + k;
        rwin[i] = (k < 17 && cc < NC)          // wave-uniform guard
                  ? ((const float4*)r)[(size_t)cc * 64 + lane]
                  : make_float4(0, 0, 0, 0);
    }
    const float4 rown = ((const float4*)r)[(size_t)(c0 + wv) * 64 + lane];

    // ---- phase 0b: pair-0 weight/act loads (stay in flight through phase 1/2)
    const size_t rowBase = (size_t)c0 * CHUNK;
    const float4* wp0 = (const float4*)(wgt + (rowBase + 2 * (size_t)tid) * A_DIM);
    float4 a0[9];
    #pragma unroll
    for (int q = 0; q < 9; ++q) a0[q] = wp0[q];
    const int2 aa0 = *(const int2*)(act + rowBase + 2 * tid);

    // ---- phase 1: window chunk sums ----
    #pragma unroll
    for (int i = 0; i < 5; ++i) {
        const int k = wv + 4 * i;
        if (k < 17) {
            double val = w4 * ((double)rwin[i].x + g * ((double)rwin[i].y +
                         g * ((double)rwin[i].z + g * (double)rwin[i].w)));
            #pragma unroll
            for (int off = 32; off > 0; off >>= 1) val += __shfl_down(val, off, 64);
            if (lane == 0) ldsL[k] = val;
        }
    }
    __syncthreads();

    // ---- phase 2: own-chunk d (wave wv -> chunk c0+wv), bit-exact scan ----
    {
        double acc_c = 0.0, wG = 1.0;
        #pragma unroll
        for (int m = 0; m < KTR; ++m) { acc_c += wG * ldsL[wv + m]; wG *= G_; }
        const double u3 = (double)rown.w;
        const double u2 = (double)rown.z + g * u3;
        const double u1 = (double)rown.y + g * u2;
        const double u0 = (double)rown.x + g * u1;
        double S = w4 * u0;
        #pragma unroll
        for (int off = 1; off < 64; off <<= 1) {
            const double t = __shfl_down(S, off, 64);
            S += (lane + off < 64) ? t : 0.0;
        }
        double Snext = __shfl_down(S, 1, 64);
        if (lane == 63) Snext = 0.0;
        const double A  = (1.0 / w4) * (Snext + G_ * acc_c);
        const double ig = 1.0 / g;
        double* dp = ldsD + wv * CHUNK + 4 * lane;
        dp[0] = u0 + A;
        dp[1] = u1 + ig * A;
        dp[2] = u2 + (ig * ig) * A;
        dp[3] = u3 + (ig * ig * ig) * A;
    }
    __syncthreads();

    // ---- phase 3: logsumexp on two row-pairs ----
    // issue pair-1 loads first so they overlap pair-0 compute
    const float4* wp1 = (const float4*)(wgt + (rowBase + 512 + 2 * (size_t)tid) * A_DIM);
    float4 a1[9];
    #pragma unroll
    for (int q = 0; q < 9; ++q) a1[q] = wp1[q];
    const int2    aa1 = *(const int2*)(act + rowBase + 512 + 2 * tid);
    const double2 dd0 = *(const double2*)(ldsD + 2 * tid);
    const double2 dd1 = *(const double2*)(ldsD + 512 + 2 * tid);

    double s_n = 0.0, s_nd = 0.0;
    double s_d = dd0.x + dd0.y + dd1.x + dd1.y;
    float w[36];
    // pair 0
    #pragma unroll
    for (int q = 0; q < 9; ++q) {
        w[4*q+0] = a0[q].x; w[4*q+1] = a0[q].y; w[4*q+2] = a0[q].z; w[4*q+3] = a0[q].w;
    }
    {   // row 0 (exact reference op order)
        float mx = w[0];
        #pragma unroll
        for (int j = 1; j < A_DIM; ++j) mx = fmaxf(mx, w[j]);
        float s = 0.0f, wsel = 0.0f;
        #pragma unroll
        for (int j = 0; j < A_DIM; ++j) { s += expf(w[j] - mx); wsel = (j == aa0.x) ? w[j] : wsel; }
        const float nlp = mx + logf(s) - wsel;
        s_n += (double)nlp;  s_nd += (double)nlp * dd0.x;
    }
    {   // row 1
        float mx = w[18];
        #pragma unroll
        for (int j = 1; j < A_DIM; ++j) mx = fmaxf(mx, w[18 + j]);
        float s = 0.0f, wsel = 0.0f;
        #pragma unroll
        for (int j = 0; j < A_DIM; ++j) { s += expf(w[18 + j] - mx); wsel = (j == aa0.y) ? w[18 + j] : wsel; }
        const float nlp = mx + logf(s) - wsel;
        s_n += (double)nlp;  s_nd += (double)nlp * dd0.y;
    }
    // pair 1
    #pragma unroll
    for (int q = 0; q < 9; ++q) {
        w[4*q+0] = a1[q].x; w[4*q+1] = a1[q].y; w[4*q+2] = a1[q].z; w[4*q+3] = a1[q].w;
    }
    {   // row 2
        float mx = w[0];
        #pragma unroll
        for (int j = 1; j < A_DIM; ++j) mx = fmaxf(mx, w[j]);
        float s = 0.0f, wsel = 0.0f;
        #pragma unroll
        for (int j = 0; j < A_DIM; ++j) { s += expf(w[j] - mx); wsel = (j == aa1.x) ? w[j] : wsel; }
        const float nlp = mx + logf(s) - wsel;
        s_n += (double)nlp;  s_nd += (double)nlp * dd1.x;
    }
    {   // row 3
        float mx = w[18];
        #pragma unroll
        for (int j = 1; j < A_DIM; ++j) mx = fmaxf(mx, w[18 + j]);
        float s = 0.0f, wsel = 0.0f;
        #pragma unroll
        for (int j = 0; j < A_DIM; ++j) { s += expf(w[18 + j] - mx); wsel = (j == aa1.y) ? w[18 + j] : wsel; }
        const float nlp = mx + logf(s) - wsel;
        s_n += (double)nlp;  s_nd += (double)nlp * dd1.y;
    }

    // ---- epilogue: block reduce, device atomics, last-block finalize ----
    #pragma unroll
    for (int off = 32; off > 0; off >>= 1) {
        s_d  += __shfl_down(s_d,  off, 64);
        s_n  += __shfl_down(s_n,  off, 64);
        s_nd += __shfl_down(s_nd, off, 64);
    }
    if (lane == 0) { red[wv*3+0] = s_d; red[wv*3+1] = s_n; red[wv*3+2] = s_nd; }
    __syncthreads();
    if (tid == 0) {
        double pa = 0.0, pb = 0.0, pc = 0.0;
        #pragma unroll
        for (int q = 0; q < 4; ++q) { pa += red[q*3]; pb += red[q*3+1]; pc += red[q*3+2]; }
        atomicAdd(&acc[0], pa);
        atomicAdd(&acc[1], pb);
        atomicAdd(&acc[2], pc);
        __threadfence();                       // value-atomics visible before flag
        const unsigned int old = atomicAdd(flag, 1u);
        if (old == NB - 1) {                   // I am the last block
            __threadfence();
            const double sd  = atomicAdd(&acc[0], 0.0);  // coherent RMW read
            const double sn  = atomicAdd(&acc[1], 0.0);
            const double snd = atomicAdd(&acc[2], 0.0);
            const double invT = 1.0 / (double)T_TOTAL;
            // out = (1/T) * ( sum(nlp*d) - mean(d) * sum(nlp) )
            out[0] = (float)((snd - (sd * invT) * sn) * invT);
        }
    }
}

// ---------------------------------------------------------------------------
extern "C" void kernel_launch(void* const* d_in, const int* in_sizes, int n_in,
                              void* d_out, int out_size, void* d_ws, size_t ws_size,
                              hipStream_t stream) {
    const float* weight = (const float*)d_in[0];   // [T, 18] f32
    const float* ep_rs  = (const float*)d_in[1];   // [T] f32
    const int*   ep_as  = (const int*)  d_in[2];   // [T] int
    float* out = (float*)d_out;

    double*       acc  = (double*)d_ws;            // acc[0..2]: sum d / nlp / nlp*d
    unsigned int* flag = (unsigned int*)((char*)d_ws + 24);

    // zero accumulators + completion flag (workspace is poisoned every iter)
    hipMemsetAsync(d_ws, 0, 64, stream);
    k_mega<<<NB, BLK, 0, stream>>>(weight, ep_as, ep_rs, acc, flag, out);
}

// Round 8
// 231.882 us; speedup vs baseline: 1.3911x; 1.3911x over previous
//
#include <hip/hip_runtime.h>
#include <math.h>

// Problem constants (from setup_inputs)
#define T_TOTAL 2097152
#define A_DIM   18
#define GAMMA_D 0.99

#define CHUNK 256
#define NC    (T_TOTAL / CHUNK)        // 8192 chunks
#define KTR   14                       // G^14 ~ 2e-16, G = 0.99^256 ~ 0.076
#define CPB   4                        // chunks per block
#define NB    (NC / CPB)               // 2048 blocks

// ---------------------------------------------------------------------------
// R5-proven fused kernel (232.6 us champion), ONE change: native-transcendental
// logsumexp (__expf/__logf -> v_exp_f32/v_log_f32) to cut the ~24 us of ocml
// VALU time identified by R6/R7 counters (VALUBusy 14-17% at 163-168 us with
// near-zero HBM traffic). Atomic finalize REVERTED: R6/R7 proved 8192
// same-address device atomics cost ~100 us of serialized tail.
__global__ __launch_bounds__(256, 4)
void k_mega(const float* __restrict__ wgt, const int* __restrict__ act,
            const float* __restrict__ r, double* __restrict__ partials) {
    __shared__ double ldsL[17];               // window chunk-sums
    __shared__ double ldsD[CPB * CHUNK];      // d for the block's 1024 rows (8 KB)
    __shared__ double red[12];
    const int tid  = threadIdx.x;
    const int lane = tid & 63, wv = tid >> 6;
    const int c0   = blockIdx.x * CPB;
    const double g  = GAMMA_D;
    const double G_ = pow(g, 256.0);
    const double w4 = pow(g, (double)(4 * lane));

    // ---- phase 0: issue pair-0 weight/act loads early ----
    const size_t rowBase = (size_t)c0 * CHUNK;
    const float4* wp0 = (const float4*)(wgt + (rowBase + 2 * (size_t)tid) * A_DIM);
    float4 a0[9];
    #pragma unroll
    for (int q = 0; q < 9; ++q) a0[q] = wp0[q];
    const int2 aa0 = *(const int2*)(act + rowBase + 2 * tid);

    // ---- phase 1: window L (wave wv handles k = wv, wv+4, ...) ----
    #pragma unroll
    for (int i = 0; i < 5; ++i) {
        const int k  = wv + 4 * i;
        const int cc = c0 + 1 + k;
        if (k < 17) {
            double val = 0.0;
            if (cc < NC) {                    // wave-uniform guard
                const float4 v = ((const float4*)r)[(size_t)cc * 64 + lane];
                val = w4 * ((double)v.x + g * ((double)v.y + g * ((double)v.z + g * (double)v.w)));
                #pragma unroll
                for (int off = 32; off > 0; off >>= 1) val += __shfl_down(val, off, 64);
            }
            if (lane == 0) ldsL[k] = val;
        }
    }
    __syncthreads();

    // ---- phase 2: own-chunk d (wave wv -> chunk c0+wv), bit-exact scan ----
    {
        double acc = 0.0, wG = 1.0;
        #pragma unroll
        for (int m = 0; m < KTR; ++m) { acc += wG * ldsL[wv + m]; wG *= G_; }
        const int c = c0 + wv;
        const float4 v = ((const float4*)r)[(size_t)c * 64 + lane];
        const double u3 = (double)v.w;
        const double u2 = (double)v.z + g * u3;
        const double u1 = (double)v.y + g * u2;
        const double u0 = (double)v.x + g * u1;
        double S = w4 * u0;
        #pragma unroll
        for (int off = 1; off < 64; off <<= 1) {
            const double t = __shfl_down(S, off, 64);
            S += (lane + off < 64) ? t : 0.0;
        }
        double Snext = __shfl_down(S, 1, 64);
        if (lane == 63) Snext = 0.0;
        const double A  = (1.0 / w4) * (Snext + G_ * acc);
        const double ig = 1.0 / g;
        double* dp = ldsD + wv * CHUNK + 4 * lane;
        dp[0] = u0 + A;
        dp[1] = u1 + ig * A;
        dp[2] = u2 + (ig * ig) * A;
        dp[3] = u3 + (ig * ig * ig) * A;
    }
    __syncthreads();

    // ---- phase 3: logsumexp on two row-pairs (native transcendentals) ----
    const float4* wp1 = (const float4*)(wgt + (rowBase + 512 + 2 * (size_t)tid) * A_DIM);
    float4 a1[9];
    #pragma unroll
    for (int q = 0; q < 9; ++q) a1[q] = wp1[q];
    const int2    aa1 = *(const int2*)(act + rowBase + 512 + 2 * tid);
    const double2 dd0 = *(const double2*)(ldsD + 2 * tid);
    const double2 dd1 = *(const double2*)(ldsD + 512 + 2 * tid);

    double s_n = 0.0, s_nd = 0.0;
    double s_d = dd0.x + dd0.y + dd1.x + dd1.y;
    float w[36];
    // pair 0
    #pragma unroll
    for (int q = 0; q < 9; ++q) {
        w[4*q+0] = a0[q].x; w[4*q+1] = a0[q].y; w[4*q+2] = a0[q].z; w[4*q+3] = a0[q].w;
    }
    {   // row 0
        float mx = w[0];
        #pragma unroll
        for (int j = 1; j < A_DIM; ++j) mx = fmaxf(mx, w[j]);
        float s = 0.0f, wsel = 0.0f;
        #pragma unroll
        for (int j = 0; j < A_DIM; ++j) { s += __expf(w[j] - mx); wsel = (j == aa0.x) ? w[j] : wsel; }
        const float nlp = mx + __logf(s) - wsel;
        s_n += (double)nlp;  s_nd += (double)nlp * dd0.x;
    }
    {   // row 1
        float mx = w[18];
        #pragma unroll
        for (int j = 1; j < A_DIM; ++j) mx = fmaxf(mx, w[18 + j]);
        float s = 0.0f, wsel = 0.0f;
        #pragma unroll
        for (int j = 0; j < A_DIM; ++j) { s += __expf(w[18 + j] - mx); wsel = (j == aa0.y) ? w[18 + j] : wsel; }
        const float nlp = mx + __logf(s) - wsel;
        s_n += (double)nlp;  s_nd += (double)nlp * dd0.y;
    }
    // pair 1
    #pragma unroll
    for (int q = 0; q < 9; ++q) {
        w[4*q+0] = a1[q].x; w[4*q+1] = a1[q].y; w[4*q+2] = a1[q].z; w[4*q+3] = a1[q].w;
    }
    {   // row 2
        float mx = w[0];
        #pragma unroll
        for (int j = 1; j < A_DIM; ++j) mx = fmaxf(mx, w[j]);
        float s = 0.0f, wsel = 0.0f;
        #pragma unroll
        for (int j = 0; j < A_DIM; ++j) { s += __expf(w[j] - mx); wsel = (j == aa1.x) ? w[j] : wsel; }
        const float nlp = mx + __logf(s) - wsel;
        s_n += (double)nlp;  s_nd += (double)nlp * dd1.x;
    }
    {   // row 3
        float mx = w[18];
        #pragma unroll
        for (int j = 1; j < A_DIM; ++j) mx = fmaxf(mx, w[18 + j]);
        float s = 0.0f, wsel = 0.0f;
        #pragma unroll
        for (int j = 0; j < A_DIM; ++j) { s += __expf(w[18 + j] - mx); wsel = (j == aa1.y) ? w[18 + j] : wsel; }
        const float nlp = mx + __logf(s) - wsel;
        s_n += (double)nlp;  s_nd += (double)nlp * dd1.y;
    }

    // block reduction
    #pragma unroll
    for (int off = 32; off > 0; off >>= 1) {
        s_d  += __shfl_down(s_d,  off, 64);
        s_n  += __shfl_down(s_n,  off, 64);
        s_nd += __shfl_down(s_nd, off, 64);
    }
    if (lane == 0) { red[wv*3+0] = s_d; red[wv*3+1] = s_n; red[wv*3+2] = s_nd; }
    __syncthreads();
    if (tid == 0) {
        double a = 0.0, b = 0.0, cc = 0.0;
        #pragma unroll
        for (int q = 0; q < 4; ++q) { a += red[q*3]; b += red[q*3+1]; cc += red[q*3+2]; }
        partials[blockIdx.x*3+0] = a;
        partials[blockIdx.x*3+1] = b;
        partials[blockIdx.x*3+2] = cc;
    }
}

// ---------------------------------------------------------------------------
// Final reduce: per-block partials -> scalar.
__global__ void k_final(const double* __restrict__ partials, float* __restrict__ out) {
    __shared__ double red[12];
    const int tid = threadIdx.x;
    double a = 0.0, b = 0.0, c = 0.0;
    for (int i = tid; i < NB; i += 256) {
        a += partials[i*3+0];
        b += partials[i*3+1];
        c += partials[i*3+2];
    }
    #pragma unroll
    for (int off = 32; off > 0; off >>= 1) {
        a += __shfl_down(a, off, 64);
        b += __shfl_down(b, off, 64);
        c += __shfl_down(c, off, 64);
    }
    const int lane = tid & 63, wv = tid >> 6;
    if (lane == 0) { red[wv*3+0] = a; red[wv*3+1] = b; red[wv*3+2] = c; }
    __syncthreads();
    if (tid == 0) {
        double A_ = 0.0, B_ = 0.0, C_ = 0.0;
        #pragma unroll
        for (int i = 0; i < 4; ++i) { A_ += red[i*3]; B_ += red[i*3+1]; C_ += red[i*3+2]; }
        const double invT = 1.0 / (double)T_TOTAL;
        // out = (1/T) * ( sum(nlp*d) - mean(d) * sum(nlp) )
        out[0] = (float)((C_ - (A_ * invT) * B_) * invT);
    }
}

// ---------------------------------------------------------------------------
extern "C" void kernel_launch(void* const* d_in, const int* in_sizes, int n_in,
                              void* d_out, int out_size, void* d_ws, size_t ws_size,
                              hipStream_t stream) {
    const float* weight = (const float*)d_in[0];   // [T, 18] f32
    const float* ep_rs  = (const float*)d_in[1];   // [T] f32
    const int*   ep_as  = (const int*)  d_in[2];   // [T] int
    float* out = (float*)d_out;

    double* partials = (double*)d_ws;              // NB*3 doubles (48 KiB)

    k_mega  <<<NB, 256, 0, stream>>>(weight, ep_as, ep_rs, partials);
    k_final <<<1,  256, 0, stream>>>(partials, out);
}